// Round 17
// baseline (189.877 us; speedup 1.0000x reference)
//
#include <hip/hip_runtime.h>
#include <hip/hip_bf16.h>
#include <cstdint>

typedef __bf16 bf16;
typedef __bf16 bf16x8 __attribute__((ext_vector_type(8)));
typedef float f32x4 __attribute__((ext_vector_type(4)));
typedef float f32x8 __attribute__((ext_vector_type(8)));
typedef float f32x16 __attribute__((ext_vector_type(16)));

#define DIM   1024
#define SEQ   2048
#define BATCH 2
#define HEADS 16
#define HDIM  64

// log2(e)/sqrt(HDIM) — folded into Q at the QKV-GEMM epilogue so the
// attention kernel computes p = exp2(score) directly.
#define QSCALE 0.1803368801111204f

__device__ __forceinline__ void gload_lds16(const void* g, void* l) {
    __builtin_amdgcn_global_load_lds(
        (const __attribute__((address_space(1))) void*)g,
        (__attribute__((address_space(3))) void*)l,
        16, 0, 0);
}

__device__ __forceinline__ uint32_t pkbf(float a, float b) {
    union { bf16 h[2]; uint32_t u; } t;
    t.h[0] = (bf16)a; t.h[1] = (bf16)b;
    return t.u;
}

#define LO8(v)  __builtin_shufflevector(v, v, 0, 1, 2, 3, 4, 5, 6, 7)
#define HI8(v)  __builtin_shufflevector(v, v, 8, 9, 10, 11, 12, 13, 14, 15)
#define LO4(v)  __builtin_shufflevector(v, v, 0, 1, 2, 3)
#define HI4(v)  __builtin_shufflevector(v, v, 4, 5, 6, 7)

// ------------- convert + transpose weights: W[K][N] -> Wt[N][K] bf16 -------------
__global__ __launch_bounds__(256) void cvt_wt_kernel(const float* __restrict__ Wq,
                                                     const float* __restrict__ Wk,
                                                     const float* __restrict__ Wv,
                                                     const float* __restrict__ Wo,
                                                     bf16* __restrict__ Wt) {
    int z = blockIdx.z;
    const float* W = (z == 0) ? Wq : (z == 1) ? Wk : (z == 2) ? Wv : Wo;
    bf16* out = Wt + (size_t)z * DIM * DIM;
    int w = threadIdx.x >> 6, lane = threadIdx.x & 63;
    int n  = blockIdx.x * 64 + lane;     // output row (orig col) — lane-contig reads
    int kb = blockIdx.y * 32 + w * 8;    // 8 consecutive k per thread
    bf16x8 o;
#pragma unroll
    for (int j = 0; j < 8; ++j)
        o[j] = (bf16)W[(size_t)(kb + j) * DIM + n];   // coalesced 256B per row
    *(bf16x8*)(out + (size_t)n * DIM + kb) = o;
}

// ---------------- 128-row-tile bf16 GEMM (m97 structure) ----------------
// Bt: N x K row-major bf16 (transposed weight).
// MODE 0: tile 128x128.  A = x (f32, fused cvt in staging).  z picks
//         weight/bias/output; Q,K out row-major (B*H,S,Dh), Q pre-scaled;
//         V out FRAGMENT-MAJOR (per (head, 32-kv block): 4 KB = 4 x 1KB
//         lane-linear MFMA A-operands — R12-verified layout).
// MODE 1: tile 128x64 (512 blocks -> 2 blocks/CU).  A bf16; f32 out + bias.
template <int MODE>
__global__ __launch_bounds__(256) void gemm128_kernel(
        const void* __restrict__ Ap,
        const bf16* __restrict__ WtB,
        const float* __restrict__ b0,
        const float* __restrict__ b1,
        const float* __restrict__ b2,
        void* __restrict__ outp) {
    constexpr int K  = DIM;
    constexpr int BN = (MODE == 1) ? 64 : 128;   // block N-tile
    constexpr int NR = BN / 32;                  // col-frags per wave (2 or 4)
    int z = (MODE == 0) ? blockIdx.z : 0;
    const bf16* Bt = WtB + (size_t)z * DIM * DIM;
    const float* bias = (MODE == 0) ? ((z == 0) ? b0 : (z == 1) ? b1 : b2) : b0;

    int m0 = blockIdx.y * 128, n0 = blockIdx.x * BN;
    int tid = threadIdx.x;
    int w = tid >> 6, lane = tid & 63, l15 = lane & 15, l4 = lane >> 4;
    int wr = (w >> 1) * 64, wc = (w & 1) * (BN / 2);

    __shared__ __align__(16) bf16 As[128 * 32];
    __shared__ __align__(16) bf16 Bs[BN * 32];

    // MODE 0 fused-cvt A staging: thread -> (row, 16-k half)
    int arow = tid >> 1, acol = (tid & 1) * 16;
    const float* asrc = (MODE == 0)
        ? (const float*)Ap + (size_t)(m0 + arow) * K + acol : nullptr;

    f32x4 acc[4][NR] = {};

    for (int k0 = 0; k0 < K; k0 += 32) {
#pragma unroll
        for (int rr = 0; rr < BN / 64; ++rr) {
            int c = rr * 256 + tid;   // 16B chunk id; lane-linear in LDS
            gload_lds16(Bt + (size_t)(n0 + (c >> 2)) * K + k0 + (c & 3) * 8, &Bs[c * 8]);
        }
        if constexpr (MODE == 0) {
            // A: read x f32 directly, convert, ds_write (fused cvt_x)
            const float4* s4 = (const float4*)(asrc + k0);
            float4 f0 = s4[0], f1 = s4[1], f2 = s4[2], f3 = s4[3];
            bf16x8 e0, e1;
            e0[0] = (bf16)f0.x; e0[1] = (bf16)f0.y; e0[2] = (bf16)f0.z; e0[3] = (bf16)f0.w;
            e0[4] = (bf16)f1.x; e0[5] = (bf16)f1.y; e0[6] = (bf16)f1.z; e0[7] = (bf16)f1.w;
            e1[0] = (bf16)f2.x; e1[1] = (bf16)f2.y; e1[2] = (bf16)f2.z; e1[3] = (bf16)f2.w;
            e1[4] = (bf16)f3.x; e1[5] = (bf16)f3.y; e1[6] = (bf16)f3.z; e1[7] = (bf16)f3.w;
            *(bf16x8*)&As[arow * 32 + acol]     = e0;
            *(bf16x8*)&As[arow * 32 + acol + 8] = e1;
        } else {
            const bf16* A = (const bf16*)Ap;
#pragma unroll
            for (int rr = 0; rr < 2; ++rr) {
                int c = rr * 256 + tid;
                gload_lds16(A + (size_t)(m0 + (c >> 2)) * K + k0 + (c & 3) * 8, &As[c * 8]);
            }
        }
        __syncthreads();
        bf16x8 af[4], bfr[NR];
#pragma unroll
        for (int m = 0; m < 4; ++m)
            af[m] = *(const bf16x8*)&As[(wr + m * 16 + l15) * 32 + l4 * 8];
#pragma unroll
        for (int n = 0; n < NR; ++n)
            bfr[n] = *(const bf16x8*)&Bs[(wc + n * 16 + l15) * 32 + l4 * 8];
#pragma unroll
        for (int m = 0; m < 4; ++m)
#pragma unroll
            for (int n = 0; n < NR; ++n)
                acc[m][n] = __builtin_amdgcn_mfma_f32_16x16x32_bf16(
                    af[m], bfr[n], acc[m][n], 0, 0, 0);
        __syncthreads();
    }

    // epilogue: C/D layout col=lane&15, row=(lane>>4)*4+i  [m89-verified]
    float oscale = (MODE == 0 && z == 0) ? QSCALE : 1.0f;   // fold softmax scale into Q
#pragma unroll
    for (int n = 0; n < NR; ++n) {
        int col = n0 + wc + n * 16 + l15;
        float bv = bias[col];
#pragma unroll
        for (int m = 0; m < 4; ++m) {
            int rowb = m0 + wr + m * 16 + l4 * 4;
            if (MODE == 1) {
                float* out = (float*)outp;
#pragma unroll
                for (int i = 0; i < 4; ++i)
                    out[(size_t)(rowb + i) * DIM + col] = acc[m][n][i] + bv;
            } else if (z < 2) {   // Q, K: row-major (B*H, S, Dh); Q pre-scaled
                bf16* out = (bf16*)outp + (size_t)z * (BATCH * HEADS * SEQ * HDIM);
                int h = col >> 6, d = col & 63;
#pragma unroll
                for (int i = 0; i < 4; ++i) {
                    int row = rowb + i;
                    int bb = row >> 11, s = row & 2047;
                    out[(((size_t)(bb * HEADS + h)) * SEQ + s) * HDIM + d] =
                        (bf16)((acc[m][n][i] + bv) * oscale);
                }
            } else {              // V: fragment-major V^T A-operand layout [R12-verified]
                char* out = (char*)outp + (size_t)2 * (BATCH * HEADS * SEQ * HDIM) * 2;
                int h = col >> 6, d = col & 63;
                int dblk = d >> 5;
                int bb = rowb >> 11, s0 = rowb & 2047;
                int hb2 = bb * HEADS + h;
                int lane2 = (d & 31) + 32 * ((s0 >> 3) & 1);
                size_t off = (size_t)(hb2 * 64 + (s0 >> 5)) * 4096
                             + (dblk * 2 + ((s0 >> 4) & 1)) * 1024
                             + lane2 * 16 + (s0 & 7) * 2;
                union { bf16 hh[4]; ushort4 v; } pk;
#pragma unroll
                for (int i = 0; i < 4; ++i) pk.hh[i] = (bf16)(acc[m][n][i] + bv);
                *(ushort4*)(out + off) = pk.v;
            }
        }
    }
}

// --- flash attention, HYBRID paths (R16) + KV-SPLIT x2 for 4 waves/SIMD ---
// R16 diagnosis: all structures sit at 57us = 13.7us MFMA / 23% util —
// dependency-bound at 2 waves/SIMD.  R16's hybrid (K via LDS 32KB, V direct
// fragment-major) has VGPR=120<=128 and LDS 32KB — 4-blocks/CU CAPABLE; only
// the 512-block grid limited residency.  kv-split x2 (exact merge: no-max
// softmax partials are plain sums) -> 1024 blocks = 4 blocks/CU = 4 waves/
// SIMD.  __launch_bounds__(256,4) pins regalloc <=128.
__global__ __launch_bounds__(256, 4) void attn_kernel(const bf16* __restrict__ Q,
                                                      const bf16* __restrict__ K,
                                                      const bf16* __restrict__ Vf,
                                                      bf16* __restrict__ op0,
                                                      bf16* __restrict__ op1,
                                                      float* __restrict__ lbuf) {
    // XCD-aware bijective decode [T1; 8 XCDs]: XCD k owns heads 4k..4k+3
    int bid = blockIdx.x;                 // 0..1023
    int xcd = bid & 7, i = bid >> 3;      // 128 blocks per XCD
    int hb  = xcd * 4 + (i >> 5);
    int rem = i & 31;
    int q0  = (rem >> 1) * 128;
    int si  = rem & 1;                    // KV split index
    int kvb = si * (SEQ / 2);
    int bb = hb >> 4, h = hb & 15;
    int tid = threadIdx.x, w = tid >> 6, lane = tid & 63;
    int l31 = lane & 31, hi = lane >> 5;

    const bf16* Qh = Q + (size_t)hb * SEQ * HDIM;
    const bf16* Kh = K + (size_t)hb * SEQ * HDIM;
    const char* Vh = (const char*)Vf + (size_t)hb * 64 * 4096 + lane * 16;

    __shared__ __align__(16) bf16 Ks[2][8192];   // 128 kv x 64 dh, rows XOR-swizzled

    // Q as B-operand frags: col = q = l31, k(dh) = 16*ks + 8*hi + e
    int qrow = q0 + w * 32 + l31;
    bf16x8 qf[4];
#pragma unroll
    for (int ks = 0; ks < 4; ++ks)
        qf[ks] = *(const bf16x8*)&Qh[(size_t)qrow * HDIM + ks * 16 + hi * 8];

    f32x16 o0 = {}, o1 = {};
    float l = 0.f;                      // lane-local partial denominator

    // hoisted per-lane K staging bases (pre-swizzled global source, m173)
    const bf16* kbase[2];
    int ldsoff[2];
#pragma unroll
    for (int r = 0; r < 2; ++r) {
        int c = r * 256 + tid;                        // 0..511
        int krow = c >> 3, kj = (c & 7) ^ (krow & 7);
        kbase[r] = Kh + (size_t)krow * HDIM + kj * 8;
        ldsoff[r] = c * 8;                            // elems
    }
    auto stage = [&](bf16* ksd, int kv0) {
#pragma unroll
        for (int r = 0; r < 2; ++r) {
            gload_lds16(kbase[r] + (size_t)kv0 * HDIM,        ksd + ldsoff[r]);
            gload_lds16(kbase[r] + (size_t)(kv0 + 64) * HDIM, ksd + ldsoff[r] + 4096);
        }
    };

    // hoisted per-lane LDS read offsets (invariant across tiles)
    int koffA = l31 * 128;            // row byte offset within 64-row sub-block
    int cb[4];
#pragma unroll
    for (int ks = 0; ks < 4; ++ks)
        cb[ks] = ((2 * ks + hi) ^ (l31 & 7)) << 4;

    // one 64-kv subtile: K from LDS (kp), V direct from global (vjp = two
    // consecutive 32-kv fragment blocks of 4KB each)
    auto sub64 = [&](const char* kp, const char* vjp) {
        f32x16 s0 = {}, s1 = {};
        __builtin_amdgcn_s_setprio(1);
#pragma unroll
        for (int ks = 0; ks < 4; ++ks) {
            bf16x8 k0 = *(const bf16x8*)(kp + koffA + cb[ks]);
            bf16x8 k1 = *(const bf16x8*)(kp + koffA + 4096 + cb[ks]);
            s0 = __builtin_amdgcn_mfma_f32_32x32x16_bf16(k0, qf[ks], s0, 0, 0, 0);
            s1 = __builtin_amdgcn_mfma_f32_32x32x16_bf16(k1, qf[ks], s1, 0, 0, 0);
        }
        __builtin_amdgcn_s_setprio(0);

        // V fragments: 8 coalesced 1KB lane-linear loads, issued early so the
        // ~200cyc L2 latency hides under the softmax VALU below
        bf16x8 v0 = *(const bf16x8*)(vjp);
        bf16x8 v1 = *(const bf16x8*)(vjp + 1024);
        bf16x8 v2 = *(const bf16x8*)(vjp + 2048);
        bf16x8 v3 = *(const bf16x8*)(vjp + 3072);
        bf16x8 v4 = *(const bf16x8*)(vjp + 4096);
        bf16x8 v5 = *(const bf16x8*)(vjp + 5120);
        bf16x8 v6 = *(const bf16x8*)(vjp + 6144);
        bf16x8 v7 = *(const bf16x8*)(vjp + 7168);

        // p = exp2(s) directly (scale folded into Q; softmax shift-invariant,
        // scores ~N(0,1) -> no overflow risk vs f32 max)
#pragma unroll
        for (int r = 0; r < 16; ++r) {
            s0[r] = __builtin_amdgcn_exp2f(s0[r]);
            s1[r] = __builtin_amdgcn_exp2f(s1[r]);
        }

        // lane-local partial sum tree (cross-half merge deferred to the end)
        f32x16 a16 = s0 + s1;
        f32x8  a8  = LO8(a16) + HI8(a16);
        f32x4  a4  = LO4(a8) + HI4(a8);
        l += (a4[0] + a4[1]) + (a4[2] + a4[3]);

        // P (32 f32/lane) -> 4 bf16x8 frags: 16 packed casts + 8 permlane32_swap
        bf16x8 pa[4];
#pragma unroll
        for (int f2 = 0; f2 < 4; ++f2) {
            const f32x16& s = (f2 < 2) ? s0 : s1;
            int rb = (f2 & 1) * 8;
            uint32_t w0 = pkbf(s[rb + 0], s[rb + 1]), w1 = pkbf(s[rb + 2], s[rb + 3]);
            uint32_t w2 = pkbf(s[rb + 4], s[rb + 5]), w3 = pkbf(s[rb + 6], s[rb + 7]);
            asm("v_permlane32_swap_b32 %0, %1" : "+v"(w0), "+v"(w2));
            asm("v_permlane32_swap_b32 %0, %1" : "+v"(w1), "+v"(w3));
            union { uint32_t u[4]; bf16x8 v; } t2;
            t2.u[0] = w0; t2.u[1] = w1; t2.u[2] = w2; t2.u[3] = w3;
            pa[f2] = t2.v;
        }

        // O^T += V^T(A) * P^T(B): rows = dh (crow), cols = q (lane&31)
        __builtin_amdgcn_s_setprio(1);
        o0 = __builtin_amdgcn_mfma_f32_32x32x16_bf16(v0, pa[0], o0, 0, 0, 0);
        o0 = __builtin_amdgcn_mfma_f32_32x32x16_bf16(v1, pa[1], o0, 0, 0, 0);
        o1 = __builtin_amdgcn_mfma_f32_32x32x16_bf16(v2, pa[0], o1, 0, 0, 0);
        o1 = __builtin_amdgcn_mfma_f32_32x32x16_bf16(v3, pa[1], o1, 0, 0, 0);
        o0 = __builtin_amdgcn_mfma_f32_32x32x16_bf16(v4, pa[2], o0, 0, 0, 0);
        o0 = __builtin_amdgcn_mfma_f32_32x32x16_bf16(v5, pa[3], o0, 0, 0, 0);
        o1 = __builtin_amdgcn_mfma_f32_32x32x16_bf16(v6, pa[2], o1, 0, 0, 0);
        o1 = __builtin_amdgcn_mfma_f32_32x32x16_bf16(v7, pa[3], o1, 0, 0, 0);
        __builtin_amdgcn_s_setprio(0);
    };

    auto proc = [&](const char* ksb, int kv0) {
        sub64(ksb,        Vh + (size_t)(kv0 >> 5) * 4096);
        sub64(ksb + 8192, Vh + (size_t)((kv0 + 64) >> 5) * 4096);
    };

    constexpr int NT = (SEQ / 2) / 128;   // 8 double-tiles per split
    stage(Ks[0], kvb);
    __syncthreads();

    for (int t = 0; t < NT; t += 2) {
        if (t + 1 < NT) stage(Ks[1], kvb + (t + 1) * 128);
        proc((const char*)&Ks[0][0], kvb + t * 128);
        __syncthreads();
        if (t + 2 < NT) stage(Ks[0], kvb + (t + 2) * 128);
        proc((const char*)&Ks[1][0], kvb + (t + 1) * 128);
        __syncthreads();
    }

    // merge the two hi-half partials once; write UNNORMALIZED o + f32 l partials
    l += __shfl_xor(l, 32);
    bf16* op = si ? op1 : op0;
    if (hi == 0)
        lbuf[((size_t)si * BATCH * HEADS + hb) * SEQ + qrow] = l;
    size_t base = ((size_t)bb * SEQ + qrow) * DIM + h * HDIM;
#pragma unroll
    for (int g = 0; g < 4; ++g) {
        int dh0 = 8 * g + 4 * hi;
        union { bf16 hh[4]; ushort4 u; } a, b2;
#pragma unroll
        for (int i = 0; i < 4; ++i) {
            a.hh[i]  = (bf16)o0[4 * g + i];
            b2.hh[i] = (bf16)o1[4 * g + i];
        }
        *(ushort4*)&op[base + dh0]      = a.u;
        *(ushort4*)&op[base + 32 + dh0] = b2.u;
    }
}

// ---------- merge: ctx = (o0 + o1) / (l0 + l1), elementwise, 8 bf16/thread ----------
// op0 aliases ctx (in-place elementwise safe: each thread touches only its 8)
__global__ __launch_bounds__(256) void merge_kernel(const bf16* __restrict__ op0,
                                                    const bf16* __restrict__ op1,
                                                    const float* __restrict__ lbuf,
                                                    bf16* __restrict__ ctx) {
    int idx = blockIdx.x * 256 + threadIdx.x;
    size_t e8 = (size_t)idx * 8;
    int row = (int)(e8 >> 10);          // 0..4095 = bb*2048+s
    int d   = (int)(e8 & 1023);
    int h = d >> 6;
    int bb = row >> 11, s = row & 2047;
    int hb = bb * HEADS + h;
    float la = lbuf[(size_t)hb * SEQ + s];
    float lb = lbuf[((size_t)BATCH * HEADS + hb) * SEQ + s];
    float inv = 1.0f / (la + lb);
    bf16x8 a = *(const bf16x8*)&op0[e8];
    bf16x8 b = *(const bf16x8*)&op1[e8];
    bf16x8 o;
#pragma unroll
    for (int i = 0; i < 8; ++i)
        o[i] = (bf16)(((float)a[i] + (float)b[i]) * inv);
    *(bf16x8*)&ctx[e8] = o;
}

extern "C" void kernel_launch(void* const* d_in, const int* in_sizes, int n_in,
                              void* d_out, int out_size, void* d_ws, size_t ws_size,
                              hipStream_t stream) {
    const float* x  = (const float*)d_in[0];
    const float* Wq = (const float*)d_in[1];
    const float* bq = (const float*)d_in[2];
    const float* Wk = (const float*)d_in[3];
    const float* bk = (const float*)d_in[4];
    const float* Wv = (const float*)d_in[5];
    const float* bv = (const float*)d_in[6];
    const float* Wo = (const float*)d_in[7];
    const float* bo = (const float*)d_in[8];

    char* ws = (char*)d_ws;
    bf16*  op1  = (bf16*)ws;                        // [0,8M): o-partial split 1
    bf16*  Wt   = (bf16*)(ws + (8u  << 20));        // [8,16M): W^T (Wo^T at +6M)
    float* lbuf = (float*)(ws + (8u  << 20));       // [8,8.5M): l-partials (Wq^T dead)
    bf16*  Qb   = (bf16*)(ws + (16u << 20));        // [16,24M): Q row-major, pre-scaled
    bf16*  Kb   = (bf16*)(ws + (24u << 20));        // [24,32M): K row-major
    bf16*  Vf   = (bf16*)(ws + (32u << 20));        // [32,40M): V fragment-major
    bf16*  op0  = (bf16*)(ws + (40u << 20));        // [40,48M): o-partial 0 / ctx

    cvt_wt_kernel<<<dim3(16, 32, 4), 256, 0, stream>>>(Wq, Wk, Wv, Wo, Wt);
    gemm128_kernel<0><<<dim3(8, 32, 3), 256, 0, stream>>>(x, Wt, bq, bk, bv, (void*)Qb);
    attn_kernel<<<1024, 256, 0, stream>>>(Qb, Kb, Vf, op0, op1, lbuf);
    merge_kernel<<<2048, 256, 0, stream>>>(op0, op1, lbuf, op0);
    gemm128_kernel<1><<<dim3(16, 32), 256, 0, stream>>>(
        op0, Wt + (size_t)3 * DIM * DIM, bo, bo, bo, (void*)d_out);
}

// Round 18
// 127.391 us; speedup vs baseline: 1.4905x; 1.4905x over previous
//
#include <hip/hip_runtime.h>
#include <hip/hip_bf16.h>
#include <cstdint>

typedef __bf16 bf16;
typedef __bf16 bf16x8 __attribute__((ext_vector_type(8)));
typedef float f32x4 __attribute__((ext_vector_type(4)));
typedef float f32x8 __attribute__((ext_vector_type(8)));
typedef float f32x16 __attribute__((ext_vector_type(16)));

#define DIM   1024
#define SEQ   2048
#define BATCH 2
#define HEADS 16
#define HDIM  64

// log2(e)/sqrt(HDIM) — folded into Q at the QKV-GEMM epilogue so the
// attention kernel computes p = exp2(score) directly.
#define QSCALE 0.1803368801111204f

__device__ __forceinline__ void gload_lds16(const void* g, void* l) {
    __builtin_amdgcn_global_load_lds(
        (const __attribute__((address_space(1))) void*)g,
        (__attribute__((address_space(3))) void*)l,
        16, 0, 0);
}

__device__ __forceinline__ uint32_t pkbf(float a, float b) {
    union { bf16 h[2]; uint32_t u; } t;
    t.h[0] = (bf16)a; t.h[1] = (bf16)b;
    return t.u;
}

#define LO8(v)  __builtin_shufflevector(v, v, 0, 1, 2, 3, 4, 5, 6, 7)
#define HI8(v)  __builtin_shufflevector(v, v, 8, 9, 10, 11, 12, 13, 14, 15)
#define LO4(v)  __builtin_shufflevector(v, v, 0, 1, 2, 3)
#define HI4(v)  __builtin_shufflevector(v, v, 4, 5, 6, 7)

// ------------- convert + transpose weights: W[K][N] -> Wt[N][K] bf16 -------------
__global__ __launch_bounds__(256) void cvt_wt_kernel(const float* __restrict__ Wq,
                                                     const float* __restrict__ Wk,
                                                     const float* __restrict__ Wv,
                                                     const float* __restrict__ Wo,
                                                     bf16* __restrict__ Wt) {
    int z = blockIdx.z;
    const float* W = (z == 0) ? Wq : (z == 1) ? Wk : (z == 2) ? Wv : Wo;
    bf16* out = Wt + (size_t)z * DIM * DIM;
    int w = threadIdx.x >> 6, lane = threadIdx.x & 63;
    int n  = blockIdx.x * 64 + lane;     // output row (orig col) — lane-contig reads
    int kb = blockIdx.y * 32 + w * 8;    // 8 consecutive k per thread
    bf16x8 o;
#pragma unroll
    for (int j = 0; j < 8; ++j)
        o[j] = (bf16)W[(size_t)(kb + j) * DIM + n];   // coalesced 256B per row
    *(bf16x8*)(out + (size_t)n * DIM + kb) = o;
}

// ---------------- 128-row-tile bf16 GEMM (m97 structure) ----------------
// Bt: N x K row-major bf16 (transposed weight).
// MODE 0: tile 128x128.  A = x (f32, fused cvt in staging).  z picks
//         weight/bias/output; Q,K out row-major (B*H,S,Dh), Q pre-scaled;
//         V out FRAGMENT-MAJOR (per (head, 32-kv block): 4 KB = 4 x 1KB
//         lane-linear MFMA A-operands — R12-verified layout).
// MODE 1: tile 128x64 (512 blocks -> 2 blocks/CU).  A bf16; f32 out + bias.
template <int MODE>
__global__ __launch_bounds__(256) void gemm128_kernel(
        const void* __restrict__ Ap,
        const bf16* __restrict__ WtB,
        const float* __restrict__ b0,
        const float* __restrict__ b1,
        const float* __restrict__ b2,
        void* __restrict__ outp) {
    constexpr int K  = DIM;
    constexpr int BN = (MODE == 1) ? 64 : 128;   // block N-tile
    constexpr int NR = BN / 32;                  // col-frags per wave (2 or 4)
    int z = (MODE == 0) ? blockIdx.z : 0;
    const bf16* Bt = WtB + (size_t)z * DIM * DIM;
    const float* bias = (MODE == 0) ? ((z == 0) ? b0 : (z == 1) ? b1 : b2) : b0;

    int m0 = blockIdx.y * 128, n0 = blockIdx.x * BN;
    int tid = threadIdx.x;
    int w = tid >> 6, lane = tid & 63, l15 = lane & 15, l4 = lane >> 4;
    int wr = (w >> 1) * 64, wc = (w & 1) * (BN / 2);

    __shared__ __align__(16) bf16 As[128 * 32];
    __shared__ __align__(16) bf16 Bs[BN * 32];

    // MODE 0 fused-cvt A staging: thread -> (row, 16-k half)
    int arow = tid >> 1, acol = (tid & 1) * 16;
    const float* asrc = (MODE == 0)
        ? (const float*)Ap + (size_t)(m0 + arow) * K + acol : nullptr;

    f32x4 acc[4][NR] = {};

    for (int k0 = 0; k0 < K; k0 += 32) {
#pragma unroll
        for (int rr = 0; rr < BN / 64; ++rr) {
            int c = rr * 256 + tid;   // 16B chunk id; lane-linear in LDS
            gload_lds16(Bt + (size_t)(n0 + (c >> 2)) * K + k0 + (c & 3) * 8, &Bs[c * 8]);
        }
        if constexpr (MODE == 0) {
            // A: read x f32 directly, convert, ds_write (fused cvt_x)
            const float4* s4 = (const float4*)(asrc + k0);
            float4 f0 = s4[0], f1 = s4[1], f2 = s4[2], f3 = s4[3];
            bf16x8 e0, e1;
            e0[0] = (bf16)f0.x; e0[1] = (bf16)f0.y; e0[2] = (bf16)f0.z; e0[3] = (bf16)f0.w;
            e0[4] = (bf16)f1.x; e0[5] = (bf16)f1.y; e0[6] = (bf16)f1.z; e0[7] = (bf16)f1.w;
            e1[0] = (bf16)f2.x; e1[1] = (bf16)f2.y; e1[2] = (bf16)f2.z; e1[3] = (bf16)f2.w;
            e1[4] = (bf16)f3.x; e1[5] = (bf16)f3.y; e1[6] = (bf16)f3.z; e1[7] = (bf16)f3.w;
            *(bf16x8*)&As[arow * 32 + acol]     = e0;
            *(bf16x8*)&As[arow * 32 + acol + 8] = e1;
        } else {
            const bf16* A = (const bf16*)Ap;
#pragma unroll
            for (int rr = 0; rr < 2; ++rr) {
                int c = rr * 256 + tid;
                gload_lds16(A + (size_t)(m0 + (c >> 2)) * K + k0 + (c & 3) * 8, &As[c * 8]);
            }
        }
        __syncthreads();
        bf16x8 af[4], bfr[NR];
#pragma unroll
        for (int m = 0; m < 4; ++m)
            af[m] = *(const bf16x8*)&As[(wr + m * 16 + l15) * 32 + l4 * 8];
#pragma unroll
        for (int n = 0; n < NR; ++n)
            bfr[n] = *(const bf16x8*)&Bs[(wc + n * 16 + l15) * 32 + l4 * 8];
#pragma unroll
        for (int m = 0; m < 4; ++m)
#pragma unroll
            for (int n = 0; n < NR; ++n)
                acc[m][n] = __builtin_amdgcn_mfma_f32_16x16x32_bf16(
                    af[m], bfr[n], acc[m][n], 0, 0, 0);
        __syncthreads();
    }

    // epilogue: C/D layout col=lane&15, row=(lane>>4)*4+i  [m89-verified]
    float oscale = (MODE == 0 && z == 0) ? QSCALE : 1.0f;   // fold softmax scale into Q
#pragma unroll
    for (int n = 0; n < NR; ++n) {
        int col = n0 + wc + n * 16 + l15;
        float bv = bias[col];
#pragma unroll
        for (int m = 0; m < 4; ++m) {
            int rowb = m0 + wr + m * 16 + l4 * 4;
            if (MODE == 1) {
                float* out = (float*)outp;
#pragma unroll
                for (int i = 0; i < 4; ++i)
                    out[(size_t)(rowb + i) * DIM + col] = acc[m][n][i] + bv;
            } else if (z < 2) {   // Q, K: row-major (B*H, S, Dh); Q pre-scaled
                bf16* out = (bf16*)outp + (size_t)z * (BATCH * HEADS * SEQ * HDIM);
                int h = col >> 6, d = col & 63;
#pragma unroll
                for (int i = 0; i < 4; ++i) {
                    int row = rowb + i;
                    int bb = row >> 11, s = row & 2047;
                    out[(((size_t)(bb * HEADS + h)) * SEQ + s) * HDIM + d] =
                        (bf16)((acc[m][n][i] + bv) * oscale);
                }
            } else {              // V: fragment-major V^T A-operand layout [R12-verified]
                char* out = (char*)outp + (size_t)2 * (BATCH * HEADS * SEQ * HDIM) * 2;
                int h = col >> 6, d = col & 63;
                int dblk = d >> 5;
                int bb = rowb >> 11, s0 = rowb & 2047;
                int hb2 = bb * HEADS + h;
                int lane2 = (d & 31) + 32 * ((s0 >> 3) & 1);
                size_t off = (size_t)(hb2 * 64 + (s0 >> 5)) * 4096
                             + (dblk * 2 + ((s0 >> 4) & 1)) * 1024
                             + lane2 * 16 + (s0 & 7) * 2;
                union { bf16 hh[4]; ushort4 v; } pk;
#pragma unroll
                for (int i = 0; i < 4; ++i) pk.hh[i] = (bf16)(acc[m][n][i] + bv);
                *(ushort4*)(out + off) = pk.v;
            }
        }
    }
}

// --- flash attention, HYBRID paths (R16) + KV-SPLIT x2; NATURAL regalloc ---
// R17 lesson: __launch_bounds__(256,4) forced regalloc below the kernel's
// natural ~124-reg footprint -> catastrophic scratch spill (FETCH 12->180MB).
// The pin was never needed: natural VGPR (R16: 120) <= 128 already earns
// 4 waves/SIMD by HW allocation (waves halve at 64/128/256, m69); only the
// grid (1024 blocks via kv-split x2) was missing.  K via LDS (32KB, XOR-
// swizzled), V direct fragment-major, no-max softmax, exact split merge.
__global__ __launch_bounds__(256) void attn_kernel(const bf16* __restrict__ Q,
                                                   const bf16* __restrict__ K,
                                                   const bf16* __restrict__ Vf,
                                                   bf16* __restrict__ op0,
                                                   bf16* __restrict__ op1,
                                                   float* __restrict__ lbuf) {
    // XCD-aware bijective decode [T1; 8 XCDs]: XCD k owns heads 4k..4k+3
    int bid = blockIdx.x;                 // 0..1023
    int xcd = bid & 7, i = bid >> 3;      // 128 blocks per XCD
    int hb  = xcd * 4 + (i >> 5);
    int rem = i & 31;
    int q0  = (rem >> 1) * 128;
    int si  = rem & 1;                    // KV split index
    int kvb = si * (SEQ / 2);
    int bb = hb >> 4, h = hb & 15;
    int tid = threadIdx.x, w = tid >> 6, lane = tid & 63;
    int l31 = lane & 31, hi = lane >> 5;

    const bf16* Qh = Q + (size_t)hb * SEQ * HDIM;
    const bf16* Kh = K + (size_t)hb * SEQ * HDIM;
    const char* Vh = (const char*)Vf + (size_t)hb * 64 * 4096 + lane * 16;

    __shared__ __align__(16) bf16 Ks[2][8192];   // 128 kv x 64 dh, rows XOR-swizzled

    // Q as B-operand frags: col = q = l31, k(dh) = 16*ks + 8*hi + e
    int qrow = q0 + w * 32 + l31;
    bf16x8 qf[4];
#pragma unroll
    for (int ks = 0; ks < 4; ++ks)
        qf[ks] = *(const bf16x8*)&Qh[(size_t)qrow * HDIM + ks * 16 + hi * 8];

    f32x16 o0 = {}, o1 = {};
    float l = 0.f;                      // lane-local partial denominator

    // hoisted per-lane K staging bases (pre-swizzled global source, m173)
    const bf16* kbase[2];
    int ldsoff[2];
#pragma unroll
    for (int r = 0; r < 2; ++r) {
        int c = r * 256 + tid;                        // 0..511
        int krow = c >> 3, kj = (c & 7) ^ (krow & 7);
        kbase[r] = Kh + (size_t)krow * HDIM + kj * 8;
        ldsoff[r] = c * 8;                            // elems
    }
    auto stage = [&](bf16* ksd, int kv0) {
#pragma unroll
        for (int r = 0; r < 2; ++r) {
            gload_lds16(kbase[r] + (size_t)kv0 * HDIM,        ksd + ldsoff[r]);
            gload_lds16(kbase[r] + (size_t)(kv0 + 64) * HDIM, ksd + ldsoff[r] + 4096);
        }
    };

    // hoisted per-lane LDS read offsets (invariant across tiles)
    int koffA = l31 * 128;            // row byte offset within 64-row sub-block
    int cb[4];
#pragma unroll
    for (int ks = 0; ks < 4; ++ks)
        cb[ks] = ((2 * ks + hi) ^ (l31 & 7)) << 4;

    // one 64-kv subtile: K from LDS (kp), V direct from global (vjp = two
    // consecutive 32-kv fragment blocks of 4KB each)
    auto sub64 = [&](const char* kp, const char* vjp) {
        f32x16 s0 = {}, s1 = {};
        __builtin_amdgcn_s_setprio(1);
#pragma unroll
        for (int ks = 0; ks < 4; ++ks) {
            bf16x8 k0 = *(const bf16x8*)(kp + koffA + cb[ks]);
            bf16x8 k1 = *(const bf16x8*)(kp + koffA + 4096 + cb[ks]);
            s0 = __builtin_amdgcn_mfma_f32_32x32x16_bf16(k0, qf[ks], s0, 0, 0, 0);
            s1 = __builtin_amdgcn_mfma_f32_32x32x16_bf16(k1, qf[ks], s1, 0, 0, 0);
        }
        __builtin_amdgcn_s_setprio(0);

        // V fragments: 8 coalesced 1KB lane-linear loads, issued early so the
        // ~200cyc L2 latency hides under the softmax VALU below
        bf16x8 v0 = *(const bf16x8*)(vjp);
        bf16x8 v1 = *(const bf16x8*)(vjp + 1024);
        bf16x8 v2 = *(const bf16x8*)(vjp + 2048);
        bf16x8 v3 = *(const bf16x8*)(vjp + 3072);
        bf16x8 v4 = *(const bf16x8*)(vjp + 4096);
        bf16x8 v5 = *(const bf16x8*)(vjp + 5120);
        bf16x8 v6 = *(const bf16x8*)(vjp + 6144);
        bf16x8 v7 = *(const bf16x8*)(vjp + 7168);

        // p = exp2(s) directly (scale folded into Q; softmax shift-invariant,
        // scores ~N(0,1) -> no overflow risk vs f32 max)
#pragma unroll
        for (int r = 0; r < 16; ++r) {
            s0[r] = __builtin_amdgcn_exp2f(s0[r]);
            s1[r] = __builtin_amdgcn_exp2f(s1[r]);
        }

        // lane-local partial sum tree (cross-half merge deferred to the end)
        f32x16 a16 = s0 + s1;
        f32x8  a8  = LO8(a16) + HI8(a16);
        f32x4  a4  = LO4(a8) + HI4(a8);
        l += (a4[0] + a4[1]) + (a4[2] + a4[3]);

        // P (32 f32/lane) -> 4 bf16x8 frags: 16 packed casts + 8 permlane32_swap
        bf16x8 pa[4];
#pragma unroll
        for (int f2 = 0; f2 < 4; ++f2) {
            const f32x16& s = (f2 < 2) ? s0 : s1;
            int rb = (f2 & 1) * 8;
            uint32_t w0 = pkbf(s[rb + 0], s[rb + 1]), w1 = pkbf(s[rb + 2], s[rb + 3]);
            uint32_t w2 = pkbf(s[rb + 4], s[rb + 5]), w3 = pkbf(s[rb + 6], s[rb + 7]);
            asm("v_permlane32_swap_b32 %0, %1" : "+v"(w0), "+v"(w2));
            asm("v_permlane32_swap_b32 %0, %1" : "+v"(w1), "+v"(w3));
            union { uint32_t u[4]; bf16x8 v; } t2;
            t2.u[0] = w0; t2.u[1] = w1; t2.u[2] = w2; t2.u[3] = w3;
            pa[f2] = t2.v;
        }

        // O^T += V^T(A) * P^T(B): rows = dh (crow), cols = q (lane&31)
        __builtin_amdgcn_s_setprio(1);
        o0 = __builtin_amdgcn_mfma_f32_32x32x16_bf16(v0, pa[0], o0, 0, 0, 0);
        o0 = __builtin_amdgcn_mfma_f32_32x32x16_bf16(v1, pa[1], o0, 0, 0, 0);
        o1 = __builtin_amdgcn_mfma_f32_32x32x16_bf16(v2, pa[0], o1, 0, 0, 0);
        o1 = __builtin_amdgcn_mfma_f32_32x32x16_bf16(v3, pa[1], o1, 0, 0, 0);
        o0 = __builtin_amdgcn_mfma_f32_32x32x16_bf16(v4, pa[2], o0, 0, 0, 0);
        o0 = __builtin_amdgcn_mfma_f32_32x32x16_bf16(v5, pa[3], o0, 0, 0, 0);
        o1 = __builtin_amdgcn_mfma_f32_32x32x16_bf16(v6, pa[2], o1, 0, 0, 0);
        o1 = __builtin_amdgcn_mfma_f32_32x32x16_bf16(v7, pa[3], o1, 0, 0, 0);
        __builtin_amdgcn_s_setprio(0);
    };

    auto proc = [&](const char* ksb, int kv0) {
        sub64(ksb,        Vh + (size_t)(kv0 >> 5) * 4096);
        sub64(ksb + 8192, Vh + (size_t)((kv0 + 64) >> 5) * 4096);
    };

    constexpr int NT = (SEQ / 2) / 128;   // 8 double-tiles per split
    stage(Ks[0], kvb);
    __syncthreads();

    for (int t = 0; t < NT; t += 2) {
        if (t + 1 < NT) stage(Ks[1], kvb + (t + 1) * 128);
        proc((const char*)&Ks[0][0], kvb + t * 128);
        __syncthreads();
        if (t + 2 < NT) stage(Ks[0], kvb + (t + 2) * 128);
        proc((const char*)&Ks[1][0], kvb + (t + 1) * 128);
        __syncthreads();
    }

    // merge the two hi-half partials once; write UNNORMALIZED o + f32 l partials
    l += __shfl_xor(l, 32);
    bf16* op = si ? op1 : op0;
    if (hi == 0)
        lbuf[((size_t)si * BATCH * HEADS + hb) * SEQ + qrow] = l;
    size_t base = ((size_t)bb * SEQ + qrow) * DIM + h * HDIM;
#pragma unroll
    for (int g = 0; g < 4; ++g) {
        int dh0 = 8 * g + 4 * hi;
        union { bf16 hh[4]; ushort4 u; } a, b2;
#pragma unroll
        for (int i = 0; i < 4; ++i) {
            a.hh[i]  = (bf16)o0[4 * g + i];
            b2.hh[i] = (bf16)o1[4 * g + i];
        }
        *(ushort4*)&op[base + dh0]      = a.u;
        *(ushort4*)&op[base + 32 + dh0] = b2.u;
    }
}

// ---------- merge: ctx = (o0 + o1) / (l0 + l1), elementwise, 8 bf16/thread ----------
// op0 aliases ctx (in-place elementwise safe: each thread touches only its 8)
__global__ __launch_bounds__(256) void merge_kernel(const bf16* __restrict__ op0,
                                                    const bf16* __restrict__ op1,
                                                    const float* __restrict__ lbuf,
                                                    bf16* __restrict__ ctx) {
    int idx = blockIdx.x * 256 + threadIdx.x;
    size_t e8 = (size_t)idx * 8;
    int row = (int)(e8 >> 10);          // 0..4095 = bb*2048+s
    int d   = (int)(e8 & 1023);
    int h = d >> 6;
    int bb = row >> 11, s = row & 2047;
    int hb = bb * HEADS + h;
    float la = lbuf[(size_t)hb * SEQ + s];
    float lb = lbuf[((size_t)BATCH * HEADS + hb) * SEQ + s];
    float inv = 1.0f / (la + lb);
    bf16x8 a = *(const bf16x8*)&op0[e8];
    bf16x8 b = *(const bf16x8*)&op1[e8];
    bf16x8 o;
#pragma unroll
    for (int i = 0; i < 8; ++i)
        o[i] = (bf16)(((float)a[i] + (float)b[i]) * inv);
    *(bf16x8*)&ctx[e8] = o;
}

extern "C" void kernel_launch(void* const* d_in, const int* in_sizes, int n_in,
                              void* d_out, int out_size, void* d_ws, size_t ws_size,
                              hipStream_t stream) {
    const float* x  = (const float*)d_in[0];
    const float* Wq = (const float*)d_in[1];
    const float* bq = (const float*)d_in[2];
    const float* Wk = (const float*)d_in[3];
    const float* bk = (const float*)d_in[4];
    const float* Wv = (const float*)d_in[5];
    const float* bv = (const float*)d_in[6];
    const float* Wo = (const float*)d_in[7];
    const float* bo = (const float*)d_in[8];

    char* ws = (char*)d_ws;
    bf16*  op1  = (bf16*)ws;                        // [0,8M): o-partial split 1
    bf16*  Wt   = (bf16*)(ws + (8u  << 20));        // [8,16M): W^T (Wo^T at +6M)
    float* lbuf = (float*)(ws + (8u  << 20));       // [8,8.5M): l-partials (Wq^T dead)
    bf16*  Qb   = (bf16*)(ws + (16u << 20));        // [16,24M): Q row-major, pre-scaled
    bf16*  Kb   = (bf16*)(ws + (24u << 20));        // [24,32M): K row-major
    bf16*  Vf   = (bf16*)(ws + (32u << 20));        // [32,40M): V fragment-major
    bf16*  op0  = (bf16*)(ws + (40u << 20));        // [40,48M): o-partial 0 / ctx

    cvt_wt_kernel<<<dim3(16, 32, 4), 256, 0, stream>>>(Wq, Wk, Wv, Wo, Wt);
    gemm128_kernel<0><<<dim3(8, 32, 3), 256, 0, stream>>>(x, Wt, bq, bk, bv, (void*)Qb);
    attn_kernel<<<1024, 256, 0, stream>>>(Qb, Kb, Vf, op0, op1, lbuf);
    merge_kernel<<<2048, 256, 0, stream>>>(op0, op1, lbuf, op0);
    gemm128_kernel<1><<<dim3(16, 32), 256, 0, stream>>>(
        op0, Wt + (size_t)3 * DIM * DIM, bo, bo, bo, (void*)d_out);
}

// Round 19
// 120.280 us; speedup vs baseline: 1.5786x; 1.0591x over previous
//
#include <hip/hip_runtime.h>
#include <hip/hip_bf16.h>
#include <cstdint>

typedef __bf16 bf16;
typedef __bf16 bf16x8 __attribute__((ext_vector_type(8)));
typedef float f32x4 __attribute__((ext_vector_type(4)));
typedef float f32x8 __attribute__((ext_vector_type(8)));
typedef float f32x16 __attribute__((ext_vector_type(16)));

#define DIM   1024
#define SEQ   2048
#define BATCH 2
#define HEADS 16
#define HDIM  64

// log2(e)/sqrt(HDIM) — folded into Q at the QKV-GEMM epilogue so the
// attention kernel computes p = exp2(score) directly.
#define QSCALE 0.1803368801111204f

__device__ __forceinline__ void gload_lds16(const void* g, void* l) {
    __builtin_amdgcn_global_load_lds(
        (const __attribute__((address_space(1))) void*)g,
        (__attribute__((address_space(3))) void*)l,
        16, 0, 0);
}

__device__ __forceinline__ uint32_t pkbf(float a, float b) {
    union { bf16 h[2]; uint32_t u; } t;
    t.h[0] = (bf16)a; t.h[1] = (bf16)b;
    return t.u;
}

#define LO8(v)  __builtin_shufflevector(v, v, 0, 1, 2, 3, 4, 5, 6, 7)
#define HI8(v)  __builtin_shufflevector(v, v, 8, 9, 10, 11, 12, 13, 14, 15)
#define LO4(v)  __builtin_shufflevector(v, v, 0, 1, 2, 3)
#define HI4(v)  __builtin_shufflevector(v, v, 4, 5, 6, 7)

// ------------- convert + transpose weights: W[K][N] -> Wt[N][K] bf16 -------------
__global__ __launch_bounds__(256) void cvt_wt_kernel(const float* __restrict__ Wq,
                                                     const float* __restrict__ Wk,
                                                     const float* __restrict__ Wv,
                                                     const float* __restrict__ Wo,
                                                     bf16* __restrict__ Wt) {
    int z = blockIdx.z;
    const float* W = (z == 0) ? Wq : (z == 1) ? Wk : (z == 2) ? Wv : Wo;
    bf16* out = Wt + (size_t)z * DIM * DIM;
    int w = threadIdx.x >> 6, lane = threadIdx.x & 63;
    int n  = blockIdx.x * 64 + lane;     // output row (orig col) — lane-contig reads
    int kb = blockIdx.y * 32 + w * 8;    // 8 consecutive k per thread
    bf16x8 o;
#pragma unroll
    for (int j = 0; j < 8; ++j)
        o[j] = (bf16)W[(size_t)(kb + j) * DIM + n];   // coalesced 256B per row
    *(bf16x8*)(out + (size_t)n * DIM + kb) = o;
}

// ---------------- 128-row-tile bf16 GEMM (m97 structure) ----------------
// Bt: N x K row-major bf16 (transposed weight).
// MODE 0: tile 128x128.  A = x (f32, fused cvt in staging).  z picks
//         weight/bias/output; Q,K out as (B*H,S,Dh), Q pre-scaled by QSCALE;
//         V out transposed (B*H,Dh,S).
// MODE 1: tile 128x64 (512 blocks -> 2 blocks/CU: R14 fix for the 1-wave/SIMD
//         occupancy hole).  A bf16 row-major; f32 out + bias.
template <int MODE>
__global__ __launch_bounds__(256) void gemm128_kernel(
        const void* __restrict__ Ap,
        const bf16* __restrict__ WtB,
        const float* __restrict__ b0,
        const float* __restrict__ b1,
        const float* __restrict__ b2,
        void* __restrict__ outp) {
    constexpr int K  = DIM;
    constexpr int BN = (MODE == 1) ? 64 : 128;   // block N-tile
    constexpr int NR = BN / 32;                  // col-frags per wave (2 or 4)
    int z = (MODE == 0) ? blockIdx.z : 0;
    const bf16* Bt = WtB + (size_t)z * DIM * DIM;
    const float* bias = (MODE == 0) ? ((z == 0) ? b0 : (z == 1) ? b1 : b2) : b0;

    int m0 = blockIdx.y * 128, n0 = blockIdx.x * BN;
    int tid = threadIdx.x;
    int w = tid >> 6, lane = tid & 63, l15 = lane & 15, l4 = lane >> 4;
    int wr = (w >> 1) * 64, wc = (w & 1) * (BN / 2);

    __shared__ __align__(16) bf16 As[128 * 32];
    __shared__ __align__(16) bf16 Bs[BN * 32];

    // MODE 0 fused-cvt A staging: thread -> (row, 16-k half)
    int arow = tid >> 1, acol = (tid & 1) * 16;
    const float* asrc = (MODE == 0)
        ? (const float*)Ap + (size_t)(m0 + arow) * K + acol : nullptr;

    f32x4 acc[4][NR] = {};

    for (int k0 = 0; k0 < K; k0 += 32) {
#pragma unroll
        for (int rr = 0; rr < BN / 64; ++rr) {
            int c = rr * 256 + tid;   // 16B chunk id; lane-linear in LDS
            gload_lds16(Bt + (size_t)(n0 + (c >> 2)) * K + k0 + (c & 3) * 8, &Bs[c * 8]);
        }
        if constexpr (MODE == 0) {
            // A: read x f32 directly, convert, ds_write (fused cvt_x)
            const float4* s4 = (const float4*)(asrc + k0);
            float4 f0 = s4[0], f1 = s4[1], f2 = s4[2], f3 = s4[3];
            bf16x8 e0, e1;
            e0[0] = (bf16)f0.x; e0[1] = (bf16)f0.y; e0[2] = (bf16)f0.z; e0[3] = (bf16)f0.w;
            e0[4] = (bf16)f1.x; e0[5] = (bf16)f1.y; e0[6] = (bf16)f1.z; e0[7] = (bf16)f1.w;
            e1[0] = (bf16)f2.x; e1[1] = (bf16)f2.y; e1[2] = (bf16)f2.z; e1[3] = (bf16)f2.w;
            e1[4] = (bf16)f3.x; e1[5] = (bf16)f3.y; e1[6] = (bf16)f3.z; e1[7] = (bf16)f3.w;
            *(bf16x8*)&As[arow * 32 + acol]     = e0;
            *(bf16x8*)&As[arow * 32 + acol + 8] = e1;
        } else {
            const bf16* A = (const bf16*)Ap;
#pragma unroll
            for (int rr = 0; rr < 2; ++rr) {
                int c = rr * 256 + tid;
                gload_lds16(A + (size_t)(m0 + (c >> 2)) * K + k0 + (c & 3) * 8, &As[c * 8]);
            }
        }
        __syncthreads();
        bf16x8 af[4], bfr[NR];
#pragma unroll
        for (int m = 0; m < 4; ++m)
            af[m] = *(const bf16x8*)&As[(wr + m * 16 + l15) * 32 + l4 * 8];
#pragma unroll
        for (int n = 0; n < NR; ++n)
            bfr[n] = *(const bf16x8*)&Bs[(wc + n * 16 + l15) * 32 + l4 * 8];
#pragma unroll
        for (int m = 0; m < 4; ++m)
#pragma unroll
            for (int n = 0; n < NR; ++n)
                acc[m][n] = __builtin_amdgcn_mfma_f32_16x16x32_bf16(
                    af[m], bfr[n], acc[m][n], 0, 0, 0);
        __syncthreads();
    }

    // epilogue: C/D layout col=lane&15, row=(lane>>4)*4+i  [m89-verified]
    float oscale = (MODE == 0 && z == 0) ? QSCALE : 1.0f;   // fold softmax scale into Q
#pragma unroll
    for (int n = 0; n < NR; ++n) {
        int col = n0 + wc + n * 16 + l15;
        float bv = bias[col];
#pragma unroll
        for (int m = 0; m < 4; ++m) {
            int rowb = m0 + wr + m * 16 + l4 * 4;
            if (MODE == 1) {
                float* out = (float*)outp;
#pragma unroll
                for (int i = 0; i < 4; ++i)
                    out[(size_t)(rowb + i) * DIM + col] = acc[m][n][i] + bv;
            } else if (z < 2) {   // Q, K: (B*H, S, Dh); Q pre-scaled
                bf16* out = (bf16*)outp + (size_t)z * (BATCH * HEADS * SEQ * HDIM);
                int h = col >> 6, d = col & 63;
#pragma unroll
                for (int i = 0; i < 4; ++i) {
                    int row = rowb + i;
                    int bb = row >> 11, s = row & 2047;
                    out[(((size_t)(bb * HEADS + h)) * SEQ + s) * HDIM + d] =
                        (bf16)((acc[m][n][i] + bv) * oscale);
                }
            } else {              // V: transposed (B*H, Dh, S), pack 4 consecutive s
                bf16* out = (bf16*)outp + (size_t)2 * (BATCH * HEADS * SEQ * HDIM);
                int h = col >> 6, d = col & 63;
                int bb = rowb >> 11, s0 = rowb & 2047;
                union { bf16 hh[4]; ushort4 v; } pk;
#pragma unroll
                for (int i = 0; i < 4; ++i) pk.hh[i] = (bf16)(acc[m][n][i] + bv);
                *(ushort4*)&out[(((size_t)(bb * HEADS + h)) * HDIM + d) * SEQ + s0] = pk.v;
            }
        }
    }
}

// --- flash attention, swapped-QK^T 32x32, no-max softmax, KVBLK=128, XCD-swizzled ---
// Session-best attn (56.4us): LDS-staged double-buffered K/V, XOR-swizzled,
// XCD-affine decode (XCD k owns heads 4k..4k+3; per-XCD L2 set = 2MB).
// R12-R18 established this is a plateau: five structural families (direct-
// global, fragment-major, hybrid, kv-split, 64q/wave) all land 54-59us,
// bound by cross-pipe dependency chains at an effective 2 waves/SIMD that
// no grid/VGPR combination lifted (128-reg cliff / spill / barrier-lockstep).
// Q,K: (B*H, S, Dh) bf16 (Q pre-scaled by QSCALE).  Vt: (B*H, Dh, S) bf16.
__global__ __launch_bounds__(256) void attn_kernel(const bf16* __restrict__ Q,
                                                   const bf16* __restrict__ K,
                                                   const bf16* __restrict__ Vt,
                                                   bf16* __restrict__ ctx) {
    // XCD-aware bijective decode [T1; 8 XCDs, m09]
    int bid = blockIdx.x;                 // 0..511
    int xcd = bid & 7, i = bid >> 3;      // dispatch round-robins XCDs
    int hb  = xcd * (BATCH * HEADS / 8) + (i >> 4);   // 4 heads per XCD
    int q0  = (i & 15) * 128;
    int bb = hb >> 4, h = hb & 15;
    int tid = threadIdx.x, w = tid >> 6, lane = tid & 63;
    int l31 = lane & 31, hi = lane >> 5;

    const bf16* Qh = Q  + (size_t)hb * SEQ * HDIM;
    const bf16* Kh = K  + (size_t)hb * SEQ * HDIM;
    const bf16* Vh = Vt + (size_t)hb * HDIM * SEQ;

    __shared__ __align__(16) bf16 Ks[2][8192];   // 128 kv x 64 dh, rows XOR-swizzled
    __shared__ __align__(16) bf16 Vs[2][8192];   // 2 sub-blocks of 64 dh x 64 kv, swizzled

    // Q as B-operand frags: col = q = l31, k(dh) = 16*ks + 8*hi + e
    int qrow = q0 + w * 32 + l31;
    bf16x8 qf[4];
#pragma unroll
    for (int ks = 0; ks < 4; ++ks)
        qf[ks] = *(const bf16x8*)&Qh[(size_t)qrow * HDIM + ks * 16 + hi * 8];

    f32x16 o0 = {}, o1 = {};
    float l = 0.f;                      // lane-local partial denominator

    // hoisted per-lane staging bases (pre-swizzled global source, m173)
    const bf16* kbase[2];
    const bf16* vbase[2];
    int ldsoff[2];
#pragma unroll
    for (int r = 0; r < 2; ++r) {
        int c = r * 256 + tid;                        // 0..511
        int krow = c >> 3, kj = (c & 7) ^ (krow & 7);
        kbase[r] = Kh + (size_t)krow * HDIM + kj * 8;
        int dh = (c >> 3) & 63, vj = (c & 7) ^ (dh & 7);
        vbase[r] = Vh + (size_t)dh * SEQ + vj * 8;
        ldsoff[r] = c * 8;                            // elems
    }
    auto stage = [&](bf16* ksd, bf16* vsd, int kv0) {
#pragma unroll
        for (int r = 0; r < 2; ++r) {
            gload_lds16(kbase[r] + (size_t)kv0 * HDIM,        ksd + ldsoff[r]);
            gload_lds16(kbase[r] + (size_t)(kv0 + 64) * HDIM, ksd + ldsoff[r] + 4096);
            gload_lds16(vbase[r] + kv0,                       vsd + ldsoff[r]);
            gload_lds16(vbase[r] + kv0 + 64,                  vsd + ldsoff[r] + 4096);
        }
    };

    // hoisted per-lane LDS read offsets (invariant across tiles)
    int koffA = l31 * 128;            // row byte offset within 64-row sub-block
    int cb[4];
#pragma unroll
    for (int ks = 0; ks < 4; ++ks)
        cb[ks] = ((2 * ks + hi) ^ (l31 & 7)) << 4;

    // process one 64-kv subtile (byte base sub*8192 within the buffer)
    auto sub64 = [&](const char* kp, const char* vp) {
        f32x16 s0 = {}, s1 = {};
        __builtin_amdgcn_s_setprio(1);
#pragma unroll
        for (int ks = 0; ks < 4; ++ks) {
            bf16x8 k0 = *(const bf16x8*)(kp + koffA + cb[ks]);
            bf16x8 k1 = *(const bf16x8*)(kp + koffA + 4096 + cb[ks]);
            s0 = __builtin_amdgcn_mfma_f32_32x32x16_bf16(k0, qf[ks], s0, 0, 0, 0);
            s1 = __builtin_amdgcn_mfma_f32_32x32x16_bf16(k1, qf[ks], s1, 0, 0, 0);
        }
        __builtin_amdgcn_s_setprio(0);

        // p = exp2(s) directly (scale folded into Q; softmax shift-invariant,
        // scores ~N(0,1) -> no overflow risk vs f32 max)
#pragma unroll
        for (int r = 0; r < 16; ++r) {
            s0[r] = __builtin_amdgcn_exp2f(s0[r]);
            s1[r] = __builtin_amdgcn_exp2f(s1[r]);
        }

        // lane-local partial sum tree (cross-half merge deferred to the end)
        f32x16 a16 = s0 + s1;
        f32x8  a8  = LO8(a16) + HI8(a16);
        f32x4  a4  = LO4(a8) + HI4(a8);
        l += (a4[0] + a4[1]) + (a4[2] + a4[3]);

        // P (32 f32/lane) -> 4 bf16x8 frags: 16 packed casts + 8 permlane32_swap
        bf16x8 pa[4];
#pragma unroll
        for (int f2 = 0; f2 < 4; ++f2) {
            const f32x16& s = (f2 < 2) ? s0 : s1;
            int rb = (f2 & 1) * 8;
            uint32_t w0 = pkbf(s[rb + 0], s[rb + 1]), w1 = pkbf(s[rb + 2], s[rb + 3]);
            uint32_t w2 = pkbf(s[rb + 4], s[rb + 5]), w3 = pkbf(s[rb + 6], s[rb + 7]);
            asm("v_permlane32_swap_b32 %0, %1" : "+v"(w0), "+v"(w2));
            asm("v_permlane32_swap_b32 %0, %1" : "+v"(w1), "+v"(w3));
            union { uint32_t u[4]; bf16x8 v; } t2;
            t2.u[0] = w0; t2.u[1] = w1; t2.u[2] = w2; t2.u[3] = w3;
            pa[f2] = t2.v;
        }

        // O^T += V^T(A) * P^T(B): rows = dh (crow), cols = q (lane&31)
        __builtin_amdgcn_s_setprio(1);
#pragma unroll
        for (int ks = 0; ks < 4; ++ks) {
            bf16x8 v0 = *(const bf16x8*)(vp + koffA + cb[ks]);
            bf16x8 v1 = *(const bf16x8*)(vp + koffA + 4096 + cb[ks]);
            o0 = __builtin_amdgcn_mfma_f32_32x32x16_bf16(v0, pa[ks], o0, 0, 0, 0);
            o1 = __builtin_amdgcn_mfma_f32_32x32x16_bf16(v1, pa[ks], o1, 0, 0, 0);
        }
        __builtin_amdgcn_s_setprio(0);
    };

    auto proc = [&](const char* ksb, const char* vsb) {
        sub64(ksb, vsb);                      // kv sub-block 0
        sub64(ksb + 8192, vsb + 8192);        // kv sub-block 1
    };

    constexpr int NT = SEQ / 128;   // 16 double-tiles
    stage(Ks[0], Vs[0], 0);
    __syncthreads();

    for (int t = 0; t < NT; t += 2) {
        if (t + 1 < NT) stage(Ks[1], Vs[1], (t + 1) * 128);
        proc((const char*)&Ks[0][0], (const char*)&Vs[0][0]);
        __syncthreads();
        if (t + 2 < NT) stage(Ks[0], Vs[0], (t + 2) * 128);
        proc((const char*)&Ks[1][0], (const char*)&Vs[1][0]);
        __syncthreads();
    }

    // merge the two hi-half partial denominators once, then normalize
    l += __shfl_xor(l, 32);
    float inv = 1.0f / l;
    size_t base = ((size_t)bb * SEQ + qrow) * DIM + h * HDIM;
#pragma unroll
    for (int g = 0; g < 4; ++g) {
        int dh0 = 8 * g + 4 * hi;
        union { bf16 hh[4]; ushort4 u; } a, b2;
#pragma unroll
        for (int i = 0; i < 4; ++i) {
            a.hh[i]  = (bf16)(o0[4 * g + i] * inv);
            b2.hh[i] = (bf16)(o1[4 * g + i] * inv);
        }
        *(ushort4*)&ctx[base + dh0]      = a.u;
        *(ushort4*)&ctx[base + 32 + dh0] = b2.u;
    }
}

extern "C" void kernel_launch(void* const* d_in, const int* in_sizes, int n_in,
                              void* d_out, int out_size, void* d_ws, size_t ws_size,
                              hipStream_t stream) {
    const float* x  = (const float*)d_in[0];
    const float* Wq = (const float*)d_in[1];
    const float* bq = (const float*)d_in[2];
    const float* Wk = (const float*)d_in[3];
    const float* bk = (const float*)d_in[4];
    const float* Wv = (const float*)d_in[5];
    const float* bv = (const float*)d_in[6];
    const float* Wo = (const float*)d_in[7];
    const float* bo = (const float*)d_in[8];

    char* ws = (char*)d_ws;
    bf16* Wt  = (bf16*)(ws + (8u  << 20));          //  8 MiB: W^T bf16
    bf16* Qb  = (bf16*)(ws + (16u << 20));          //  8 MiB: Q (B*H,S,Dh), pre-scaled
    bf16* Kb  = (bf16*)(ws + (24u << 20));          //  8 MiB: K (B*H,S,Dh)
    bf16* Vb  = (bf16*)(ws + (32u << 20));          //  8 MiB: V (B*H,Dh,S)
    bf16* ctx = (bf16*)(ws + (40u << 20));          //  8 MiB: ctx (B,S,D)

    cvt_wt_kernel<<<dim3(16, 32, 4), 256, 0, stream>>>(Wq, Wk, Wv, Wo, Wt);
    gemm128_kernel<0><<<dim3(8, 32, 3), 256, 0, stream>>>(x, Wt, bq, bk, bv, (void*)Qb);
    attn_kernel<<<512, 256, 0, stream>>>(Qb, Kb, Vb, ctx);
    gemm128_kernel<1><<<dim3(16, 32), 256, 0, stream>>>(
        ctx, Wt + (size_t)3 * DIM * DIM, bo, bo, bo, (void*)d_out);
}